// Round 5
// baseline (57.568 us; speedup 1.0000x reference)
//
#include <hip/hip_runtime.h>
#include <math.h>

#define B_SZ   8
#define T_SEQ  2048
#define C_DIM  400
#define H_DIM  64
#define NROWS  (B_SZ * T_SEQ)       // 16384
#define QT2    (T_SEQ / 128)        // 16 q-tiles of 128 rows
#define KPAD   416                  // 400 zero-padded to 13*32
#define LDSTR  424                  // proj LDS row stride (elems)
#define NCH    8                    // max key chunks per q-tile (256 keys each)
#define TPC    4                    // key tiles (of 64) per chunk

typedef short s8v  __attribute__((ext_vector_type(8)));   // 8 bf16 (4 VGPRs)
typedef float f32x4 __attribute__((ext_vector_type(4)));

__device__ __forceinline__ unsigned short f2bf(float f) {
    unsigned int u = __float_as_uint(f);
    u = (u + 0x7FFFu + ((u >> 16) & 1u)) >> 16;   // RNE
    return (unsigned short)u;
}

__device__ __forceinline__ unsigned cvtpk_bf16(float lo, float hi) {
    unsigned r;
    asm("v_cvt_pk_bf16_f32 %0, %1, %2" : "=v"(r) : "v"(lo), "v"(hi));
    return r;
}

// ---------------------------------------------------------------------------
// Kernel 0: Wt[m][h][k] = W_m[k][h] (bf16, k zero-padded to 416).
// Wq pre-scaled by (1/sqrt(64)) * log2(e) so softmax uses exp2 directly.
// ---------------------------------------------------------------------------
__global__ __launch_bounds__(256) void wprep_kernel(
    const float* __restrict__ Wq, const float* __restrict__ Wk,
    const float* __restrict__ Wv, unsigned short* __restrict__ Wt)
{
    int idx = blockIdx.x * 256 + threadIdx.x;          // over 3*64*416
    if (idx >= 3 * H_DIM * KPAD) return;
    int m = idx / (H_DIM * KPAD);
    int r = idx - m * (H_DIM * KPAD);
    int h = r / KPAD;
    int k = r - h * KPAD;
    const float* W = (m == 0) ? Wq : (m == 1) ? Wk : Wv;
    float v = (k < C_DIM) ? W[k * H_DIM + h] : 0.0f;
    if (m == 0) v *= 0.125f * 1.44269504088896f;       // 1/sqrt(64) * log2(e)
    Wt[idx] = f2bf(v);
}

// ---------------------------------------------------------------------------
// Kernel 1: QKV projection via MFMA.  Block = 64-row A-tile (LDS 53KB),
// wave = 3 N-frags x 4 A-row-groups -> B-frag loads amortized over 64 rows
// (40MB total B-traffic vs 160MB at 16-row tiles).
// ---------------------------------------------------------------------------
__global__ __launch_bounds__(256) void proj_kernel(
    const float* __restrict__ x, const unsigned short* __restrict__ Wt,
    unsigned short* __restrict__ Qb, unsigned short* __restrict__ Kb,
    unsigned short* __restrict__ Vt)
{
    __shared__ unsigned short xl[64 * LDSTR];          // 54,272 B
    const int tid = threadIdx.x;
    const int tile = blockIdx.x;                       // 64-row tile, 0..255

    // stage 64 rows x 400 fp32 -> bf16 LDS (pad 400..415 with zeros)
    const float4* __restrict__ x4 = (const float4*)x;
    for (int idx = tid; idx < 64 * 104; idx += 256) {
        int row = idx / 104, c4 = idx - row * 104;
        ushort4 wv;
        if (c4 < 100) {
            float4 v = x4[(size_t)(tile * 64 + row) * 100 + c4];
            wv.x = f2bf(v.x); wv.y = f2bf(v.y); wv.z = f2bf(v.z); wv.w = f2bf(v.w);
        } else { wv.x = wv.y = wv.z = wv.w = 0; }
        *(ushort4*)&xl[row * LDSTR + c4 * 4] = wv;
    }
    __syncthreads();

    const int w = tid >> 6, l = tid & 63;
    const int lr = l & 15, g = l >> 4;

    f32x4 acc[3][4];
#pragma unroll
    for (int fl = 0; fl < 3; ++fl)
#pragma unroll
        for (int rg = 0; rg < 4; ++rg) acc[fl][rg] = (f32x4)0.f;

    for (int ks = 0; ks < KPAD / 32; ++ks) {
        s8v a[4];
#pragma unroll
        for (int rg = 0; rg < 4; ++rg)
            a[rg] = *(const s8v*)&xl[(rg * 16 + lr) * LDSTR + ks * 32 + g * 8];
#pragma unroll
        for (int fl = 0; fl < 3; ++fl) {
            int f = w * 3 + fl;                         // global N-frag 0..11
            int col = (f & 3) * 16 + lr;
            const s8v b = *(const s8v*)&Wt[((size_t)(f >> 2) * H_DIM + col) * KPAD
                                           + ks * 32 + g * 8];
#pragma unroll
            for (int rg = 0; rg < 4; ++rg)
                acc[fl][rg] = __builtin_amdgcn_mfma_f32_16x16x32_bf16(a[rg], b, acc[fl][rg], 0, 0, 0);
        }
    }

#pragma unroll
    for (int fl = 0; fl < 3; ++fl) {
        int f = w * 3 + fl;
        int m = f >> 2, col = (f & 3) * 16 + lr;
#pragma unroll
        for (int rg = 0; rg < 4; ++rg)
#pragma unroll
            for (int r = 0; r < 4; ++r) {
                int row_g = tile * 64 + rg * 16 + g * 4 + r;
                unsigned short bv = f2bf(acc[fl][rg][r]);
                if (m == 0)      Qb[(size_t)row_g * H_DIM + col] = bv;
                else if (m == 1) Kb[(size_t)row_g * H_DIM + col] = bv;
                else {
                    int b = row_g >> 11, t = row_g & 2047;
                    Vt[((size_t)b * H_DIM + col) * T_SEQ + t] = bv;
                }
            }
    }
}

// ---------------------------------------------------------------------------
// Kernel 2: flash attention partials via MFMA.
// Block (c, m, b): 128 q-rows (wave = 32 q-rows = 2 Q-frags), chunk = 4
// key-tiles of 64.  Swapped QK^T -> per-lane mask/exp2/lsum; in-register
// P via cvt_pk + permlane (verified r3/r4).  K/V double-buffered in
// XOR-swizzled LDS, one barrier per tile.  MFMA:ds_read = 2:1.
// ---------------------------------------------------------------------------
__global__ __launch_bounds__(256) void attn_kernel(
    const unsigned short* __restrict__ Qb, const unsigned short* __restrict__ Kb,
    const unsigned short* __restrict__ Vt,
    float* __restrict__ Opart, float* __restrict__ lpart)
{
    const int c = blockIdx.x;
    const int m = blockIdx.y;                          // 128-row q-tile
    const int b = blockIdx.z;
    if (c * TPC > 2 * m + 1) return;                   // empty chunk
    const int kt0 = c * TPC;
    const int kend = min(kt0 + (TPC - 1), 2 * m + 1);

    __shared__ char smem[2][16384];                    // 2 x (K 8KB + V 8KB)

    const int tid = threadIdx.x;
    const int w = tid >> 6, l = tid & 63;
    const int lr = l & 15, g = l >> 4;
    const int q0 = m * 128 + w * 32;                   // wave's first q-row

    // staging geometry: thread covers rows r0, r0+32 of K and of V
    const int r0 = tid >> 3;                           // 0..31
    const int ch = tid & 7;
    const int swz = (ch * 16) ^ ((r0 & 7) << 4);       // (r0+32)&7 == r0&7
    const char* const Kg = (const char*)(Kb + (size_t)b * T_SEQ * H_DIM);
    const char* const Vg = (const char*)(Vt + (size_t)b * H_DIM * T_SEQ);

    uint4 kA, kB, vA, vB;
    auto LD = [&](int kt) {
        kA = *(const uint4*)(Kg + (size_t)(kt * 64 + r0     ) * 128 + ch * 16);
        kB = *(const uint4*)(Kg + (size_t)(kt * 64 + r0 + 32) * 128 + ch * 16);
        vA = *(const uint4*)(Vg + (size_t)(r0     ) * 4096 + kt * 128 + ch * 16);
        vB = *(const uint4*)(Vg + (size_t)(r0 + 32) * 4096 + kt * 128 + ch * 16);
    };
    auto ST = [&](int buf) {
        char* Kl = smem[buf];
        char* Vl = smem[buf] + 8192;
        *(uint4*)(Kl + r0 * 128 + swz)        = kA;
        *(uint4*)(Kl + (r0 + 32) * 128 + swz) = kB;
        *(uint4*)(Vl + r0 * 128 + swz)        = vA;
        *(uint4*)(Vl + (r0 + 32) * 128 + swz) = vB;
    };

    // Q B-frags: aq[qf][s], cols q0+qf*16+lr (pre-scaled bf16)
    s8v aq[2][2];
#pragma unroll
    for (int qf = 0; qf < 2; ++qf)
#pragma unroll
        for (int s = 0; s < 2; ++s)
            aq[qf][s] = *(const s8v*)&Qb[((size_t)b * T_SEQ + q0 + qf * 16 + lr) * H_DIM
                                         + s * 32 + g * 8];

    f32x4 acc[2][4];
#pragma unroll
    for (int qf = 0; qf < 2; ++qf)
#pragma unroll
        for (int f = 0; f < 4; ++f) acc[qf][f] = (f32x4)0.f;
    float lsum[2] = {0.f, 0.f};

    LD(kt0); ST(0);
    __syncthreads();
    int cur = 0;

    for (int kt = kt0; kt <= kend; ++kt) {
        if (kt < kend) LD(kt + 1);                     // issue early (T14)
        char* const Kl = smem[cur];
        char* const Vl = smem[cur] + 8192;

        // ---- S^T = K Q^T : sacc[f][qf][r] = S[key=kt*64+f*16+g*4+r][q0+qf*16+lr]
        f32x4 sacc[4][2];
#pragma unroll
        for (int f = 0; f < 4; ++f)
#pragma unroll
            for (int qf = 0; qf < 2; ++qf) sacc[f][qf] = (f32x4)0.f;
        __builtin_amdgcn_s_setprio(1);
#pragma unroll
        for (int f = 0; f < 4; ++f)
#pragma unroll
            for (int s = 0; s < 2; ++s) {
                const s8v ak = *(const s8v*)(Kl + (f * 16 + lr) * 128
                                             + (((s * 4 + g) * 16) ^ ((lr & 7) << 4)));
#pragma unroll
                for (int qf = 0; qf < 2; ++qf)
                    sacc[f][qf] = __builtin_amdgcn_mfma_f32_16x16x32_bf16(ak, aq[qf][s], sacc[f][qf], 0, 0, 0);
            }
        __builtin_amdgcn_s_setprio(0);

        // ---- mask + exp2 + lsum (per-lane), then P->bf16 A-frags in-register
        s8v ap[2][2];
#pragma unroll
        for (int s = 0; s < 2; ++s)
#pragma unroll
            for (int qf = 0; qf < 2; ++qf) {
                const int q_my = q0 + qf * 16 + lr;
                const bool dg = (kt * 64 + 63) > (q0 + qf * 16);
                float p[8];
#pragma unroll
                for (int fh = 0; fh < 2; ++fh) {
                    const int f = 2 * s + fh;
#pragma unroll
                    for (int r = 0; r < 4; ++r) {
                        float pv = __builtin_amdgcn_exp2f(sacc[f][qf][r]);
                        if (dg && (kt * 64 + f * 16 + g * 4 + r) > q_my) pv = 0.0f;
                        p[fh * 4 + r] = pv;
                        lsum[qf] += pv;
                    }
                }
                unsigned Fa = cvtpk_bf16(p[0], p[1]);
                unsigned Fb = cvtpk_bf16(p[2], p[3]);
                unsigned Ga = cvtpk_bf16(p[4], p[5]);
                unsigned Gb = cvtpk_bf16(p[6], p[7]);
                asm("v_permlane32_swap_b32 %0, %1" : "+v"(Fa), "+v"(Ga));
                asm("v_permlane16_swap_b32 %0, %1" : "+v"(Fa), "+v"(Ga));
                asm("v_permlane32_swap_b32 %0, %1" : "+v"(Fb), "+v"(Gb));
                asm("v_permlane16_swap_b32 %0, %1" : "+v"(Fb), "+v"(Gb));
                unsigned wds[4] = { Fa, Fb, Ga, Gb };
                ap[qf][s] = *(const s8v*)wds;
            }

        // ---- O += P V : bv shared across the 2 q-frags
        __builtin_amdgcn_s_setprio(1);
#pragma unroll
        for (int f = 0; f < 4; ++f)
#pragma unroll
            for (int s = 0; s < 2; ++s) {
                const s8v bv = *(const s8v*)(Vl + (f * 16 + lr) * 128
                                             + (((s * 4 + g) * 16) ^ ((lr & 7) << 4)));
#pragma unroll
                for (int qf = 0; qf < 2; ++qf)
                    acc[qf][f] = __builtin_amdgcn_mfma_f32_16x16x32_bf16(ap[qf][s], bv, acc[qf][f], 0, 0, 0);
            }
        __builtin_amdgcn_s_setprio(0);

        if (kt < kend) {
            ST(cur ^ 1);                               // vmcnt wait lands here
            __syncthreads();                           // single barrier per tile
            cur ^= 1;
        }
    }

    // lsum: reduce across the 4 g-groups (same q=lr)
#pragma unroll
    for (int qf = 0; qf < 2; ++qf) {
        lsum[qf] += __shfl_xor(lsum[qf], 16, 64);
        lsum[qf] += __shfl_xor(lsum[qf], 32, 64);
    }

    const size_t pb = ((size_t)(b * QT2 + m) * NCH + c);
#pragma unroll
    for (int qf = 0; qf < 2; ++qf)
#pragma unroll
        for (int f = 0; f < 4; ++f)
#pragma unroll
            for (int r = 0; r < 4; ++r)
                Opart[pb * 8192 + (w * 32 + qf * 16 + g * 4 + r) * 64 + f * 16 + lr]
                    = acc[qf][f][r];
    if (l < 16) {
        lpart[pb * 128 + w * 32 + l]      = lsum[0];
        lpart[pb * 128 + w * 32 + 16 + l] = lsum[1];
    }
}

// ---------------------------------------------------------------------------
// Kernel 3: combine partials (float4): out = sum_c O_c / sum_c l_c
// ---------------------------------------------------------------------------
__global__ __launch_bounds__(256) void combine_kernel(
    const float* __restrict__ Opart, const float* __restrict__ lpart,
    float* __restrict__ out)
{
    const int idx = blockIdx.x * 256 + threadIdx.x;    // over NROWS*16
    const int row = idx >> 4, h4 = idx & 15;
    const int b = row >> 11, t = row & 2047;
    const int m = t >> 7, r = t & 127;
    const int nch = (m >> 1) + 1;

    const float4* __restrict__ Op4 = (const float4*)Opart;
    float4 os = make_float4(0.f, 0.f, 0.f, 0.f);
    float ls = 0.f;
    const size_t base = (size_t)(b * QT2 + m) * NCH;
    for (int cc = 0; cc < nch; ++cc) {
        float4 v = Op4[(base + cc) * 2048 + r * 16 + h4];
        os.x += v.x; os.y += v.y; os.z += v.z; os.w += v.w;
        ls += lpart[(base + cc) * 128 + r];
    }
    float inv = 1.0f / ls;
    ((float4*)out)[idx] = make_float4(os.x * inv, os.y * inv, os.z * inv, os.w * inv);
}

// ---------------------------------------------------------------------------
extern "C" void kernel_launch(void* const* d_in, const int* in_sizes, int n_in,
                              void* d_out, int out_size, void* d_ws, size_t ws_size,
                              hipStream_t stream)
{
    const float* x  = (const float*)d_in[0];
    const float* Wq = (const float*)d_in[1];
    const float* Wk = (const float*)d_in[2];
    const float* Wv = (const float*)d_in[3];
    float* out = (float*)d_out;

    char* ws = (char*)d_ws;
    unsigned short* Wt = (unsigned short*)(ws);                    // 159,744 B
    unsigned short* Qb = (unsigned short*)(ws + 163840);           // 2 MB
    unsigned short* Kb = (unsigned short*)(ws + 163840 + 2097152);
    unsigned short* Vt = (unsigned short*)(ws + 163840 + 2 * 2097152);
    float* Opart = (float*)(ws + 163840 + 3 * 2097152);            // 32 MB
    float* lpart = (float*)(ws + 163840 + 3 * 2097152 + 33554432); // 512 KB

    wprep_kernel<<<(3 * H_DIM * KPAD + 255) / 256, 256, 0, stream>>>(Wq, Wk, Wv, Wt);
    proj_kernel<<<NROWS / 64, 256, 0, stream>>>(x, Wt, Qb, Kb, Vt);
    attn_kernel<<<dim3(NCH, QT2, B_SZ), 256, 0, stream>>>(Qb, Kb, Vt, Opart, lpart);
    combine_kernel<<<(NROWS * H_DIM / 4) / 256, 256, 0, stream>>>(Opart, lpart, out);
}

// Round 6
// 51.264 us; speedup vs baseline: 1.1230x; 1.1230x over previous
//
#include <hip/hip_runtime.h>
#include <math.h>

#define B_SZ   8
#define T_SEQ  2048
#define C_DIM  400
#define H_DIM  64
#define NROWS  (B_SZ * T_SEQ)       // 16384
#define QT_TILES (T_SEQ / 64)       // 32
#define KPAD   416                  // 400 zero-padded to 13*32
#define LDSTR  424                  // proj LDS row stride (elems)
#define NCH    8                    // max key chunks per q-tile
#define TPC    4                    // key tiles (of 64) per chunk

typedef short s8v  __attribute__((ext_vector_type(8)));   // 8 bf16 (4 VGPRs)
typedef float f32x4 __attribute__((ext_vector_type(4)));

__device__ __forceinline__ unsigned short f2bf(float f) {
    unsigned int u = __float_as_uint(f);
    u = (u + 0x7FFFu + ((u >> 16) & 1u)) >> 16;   // RNE
    return (unsigned short)u;
}

__device__ __forceinline__ float bf2f(unsigned short u) {
    return __uint_as_float((unsigned)u << 16);
}

__device__ __forceinline__ unsigned cvtpk_bf16(float lo, float hi) {
    unsigned r;
    asm("v_cvt_pk_bf16_f32 %0, %1, %2" : "=v"(r) : "v"(lo), "v"(hi));
    return r;
}

// ---------------------------------------------------------------------------
// Kernel 0: Wt[m][h][k] = W_m[k][h] (bf16, k zero-padded to 416).
// Wq pre-scaled by (1/sqrt(64)) * log2(e) so softmax uses exp2 directly.
// ---------------------------------------------------------------------------
__global__ __launch_bounds__(256) void wprep_kernel(
    const float* __restrict__ Wq, const float* __restrict__ Wk,
    const float* __restrict__ Wv, unsigned short* __restrict__ Wt)
{
    int idx = blockIdx.x * 256 + threadIdx.x;          // over 3*64*416
    if (idx >= 3 * H_DIM * KPAD) return;
    int m = idx / (H_DIM * KPAD);
    int r = idx - m * (H_DIM * KPAD);
    int h = r / KPAD;
    int k = r - h * KPAD;
    const float* W = (m == 0) ? Wq : (m == 1) ? Wk : Wv;
    float v = (k < C_DIM) ? W[k * H_DIM + h] : 0.0f;
    if (m == 0) v *= 0.125f * 1.44269504088896f;       // 1/sqrt(64) * log2(e)
    Wt[idx] = f2bf(v);
}

// ---------------------------------------------------------------------------
// Kernel 1: QKV projection via MFMA (round-4 16-row-tile version: 32 waves/CU;
// Wt is L2-resident so B-traffic is cheap — occupancy matters more).
// ---------------------------------------------------------------------------
__global__ __launch_bounds__(256) void proj_kernel(
    const float* __restrict__ x, const unsigned short* __restrict__ Wt,
    unsigned short* __restrict__ Qb, unsigned short* __restrict__ Kb,
    unsigned short* __restrict__ Vt)
{
    __shared__ unsigned short xl[16 * LDSTR];
    const int tid = threadIdx.x;
    const int tile = blockIdx.x;                       // 16-row tile, 0..1023

    const float4* __restrict__ x4 = (const float4*)x;
    for (int idx = tid; idx < 16 * 104; idx += 256) {
        int row = idx / 104, c4 = idx - row * 104;
        ushort4 w;
        if (c4 < 100) {
            float4 v = x4[(size_t)(tile * 16 + row) * 100 + c4];
            w.x = f2bf(v.x); w.y = f2bf(v.y); w.z = f2bf(v.z); w.w = f2bf(v.w);
        } else { w.x = w.y = w.z = w.w = 0; }
        *(ushort4*)&xl[row * LDSTR + c4 * 4] = w;
    }
    __syncthreads();

    const int w = tid >> 6, l = tid & 63;
    const int lr = l & 15, g = l >> 4;

    f32x4 acc[3];
    acc[0] = (f32x4)0.f; acc[1] = (f32x4)0.f; acc[2] = (f32x4)0.f;

    for (int ks = 0; ks < KPAD / 32; ++ks) {
        s8v a = *(const s8v*)&xl[lr * LDSTR + ks * 32 + g * 8];
#pragma unroll
        for (int fl = 0; fl < 3; ++fl) {
            int f = w * 3 + fl;                         // global N-frag 0..11
            int col = (f & 3) * 16 + lr;
            const s8v b = *(const s8v*)&Wt[((size_t)(f >> 2) * H_DIM + col) * KPAD
                                           + ks * 32 + g * 8];
            acc[fl] = __builtin_amdgcn_mfma_f32_16x16x32_bf16(a, b, acc[fl], 0, 0, 0);
        }
    }

#pragma unroll
    for (int fl = 0; fl < 3; ++fl) {
        int f = w * 3 + fl;
        int m = f >> 2, col = (f & 3) * 16 + lr;
#pragma unroll
        for (int r = 0; r < 4; ++r) {
            int row_g = tile * 16 + g * 4 + r;
            unsigned short bv = f2bf(acc[fl][r]);
            if (m == 0)      Qb[(size_t)row_g * H_DIM + col] = bv;
            else if (m == 1) Kb[(size_t)row_g * H_DIM + col] = bv;
            else {
                int b = row_g >> 11, t = row_g & 2047;
                Vt[((size_t)b * H_DIM + col) * T_SEQ + t] = bv;
            }
        }
    }
}

// ---------------------------------------------------------------------------
// Kernel 2: flash attention partials via MFMA (round-4 structure, wave=16q).
// Change vs r4: prefetch depth 2 — LD(kt+2) issued AFTER ST(cur^1), so each
// global load is in flight for a full tile + barrier before its vmcnt wait.
// Epilogue now writes Opart in bf16 (halves partial traffic).
// ---------------------------------------------------------------------------
__global__ __launch_bounds__(256) void attn_kernel(
    const unsigned short* __restrict__ Qb, const unsigned short* __restrict__ Kb,
    const unsigned short* __restrict__ Vt,
    unsigned short* __restrict__ Opart, float* __restrict__ lpart)
{
    const int c  = blockIdx.x;
    const int qt = blockIdx.y;
    const int b  = blockIdx.z;
    if (c * TPC > qt) return;                          // empty chunk
    const int kt0 = c * TPC;
    const int kend = min(kt0 + (TPC - 1), qt);

    __shared__ char smem[2][16384];                    // 2 x (K 8KB + V 8KB)

    const int tid = threadIdx.x;
    const int w = tid >> 6, l = tid & 63;
    const int lr = l & 15, g = l >> 4;
    const int q0 = qt * 64 + w * 16;                   // wave's first q-row

    // staging geometry: thread covers rows r0, r0+32 of K and of V
    const int r0 = tid >> 3;                           // 0..31
    const int ch = tid & 7;
    const int swz = (ch * 16) ^ ((r0 & 7) << 4);       // (r0+32)&7 == r0&7
    const char* const Kg = (const char*)(Kb + (size_t)b * T_SEQ * H_DIM);
    const char* const Vg = (const char*)(Vt + (size_t)b * H_DIM * T_SEQ);

    uint4 kA, kB, vA, vB;
    auto LD = [&](int kt) {
        kA = *(const uint4*)(Kg + (size_t)(kt * 64 + r0     ) * 128 + ch * 16);
        kB = *(const uint4*)(Kg + (size_t)(kt * 64 + r0 + 32) * 128 + ch * 16);
        vA = *(const uint4*)(Vg + (size_t)(r0     ) * 4096 + kt * 128 + ch * 16);
        vB = *(const uint4*)(Vg + (size_t)(r0 + 32) * 4096 + kt * 128 + ch * 16);
    };
    auto ST = [&](int buf) {
        char* Kl = smem[buf];
        char* Vl = smem[buf] + 8192;
        *(uint4*)(Kl + r0 * 128 + swz)        = kA;
        *(uint4*)(Kl + (r0 + 32) * 128 + swz) = kB;
        *(uint4*)(Vl + r0 * 128 + swz)        = vA;
        *(uint4*)(Vl + (r0 + 32) * 128 + swz) = vB;
    };

    // Q B-frags (2 k-steps): lane holds Q[q0+lr][g*8+j] — pre-scaled bf16
    s8v aq[2];
#pragma unroll
    for (int s = 0; s < 2; ++s)
        aq[s] = *(const s8v*)&Qb[((size_t)b * T_SEQ + q0 + lr) * H_DIM + s * 32 + g * 8];

    f32x4 acc[4];
#pragma unroll
    for (int f = 0; f < 4; ++f) acc[f] = (f32x4)0.f;
    float lsum = 0.f;

    LD(kt0); ST(0);                                    // prologue (one stall)
    if (kt0 < kend) LD(kt0 + 1);                       // depth-2 prefetch seed
    __syncthreads();
    int cur = 0;

    for (int kt = kt0; kt <= kend; ++kt) {
        char* const Kl = smem[cur];
        char* const Vl = smem[cur] + 8192;

        // ---- S^T = K Q^T : sacc[f][r] = S[key=kt*64+f*16+g*4+r][q=q0+lr]
        f32x4 sacc[4];
#pragma unroll
        for (int f = 0; f < 4; ++f) sacc[f] = (f32x4)0.f;
        __builtin_amdgcn_s_setprio(1);
#pragma unroll
        for (int f = 0; f < 4; ++f)
#pragma unroll
            for (int s = 0; s < 2; ++s) {
                const s8v ak = *(const s8v*)(Kl + (f * 16 + lr) * 128
                                             + (((s * 4 + g) * 16) ^ ((lr & 7) << 4)));
                sacc[f] = __builtin_amdgcn_mfma_f32_16x16x32_bf16(ak, aq[s], sacc[f], 0, 0, 0);
            }
        __builtin_amdgcn_s_setprio(0);

        // ---- mask + exp2 + lsum, per-lane
        float p[4][4];
        const bool diag = (kt == qt);
        const int q_my = q0 + lr;
#pragma unroll
        for (int f = 0; f < 4; ++f)
#pragma unroll
            for (int r = 0; r < 4; ++r) {
                float pv = __builtin_amdgcn_exp2f(sacc[f][r]);
                if (diag && (kt * 64 + f * 16 + g * 4 + r) > q_my) pv = 0.0f;
                p[f][r] = pv;
                lsum += pv;
            }

        // ---- P -> bf16 A-frags in-register (cvt_pk + permlane, verified r3/4)
        s8v ap[2];
#pragma unroll
        for (int s = 0; s < 2; ++s) {
            unsigned Fa = cvtpk_bf16(p[2 * s][0],     p[2 * s][1]);
            unsigned Fb = cvtpk_bf16(p[2 * s][2],     p[2 * s][3]);
            unsigned Ga = cvtpk_bf16(p[2 * s + 1][0], p[2 * s + 1][1]);
            unsigned Gb = cvtpk_bf16(p[2 * s + 1][2], p[2 * s + 1][3]);
            asm("v_permlane32_swap_b32 %0, %1" : "+v"(Fa), "+v"(Ga));
            asm("v_permlane16_swap_b32 %0, %1" : "+v"(Fa), "+v"(Ga));
            asm("v_permlane32_swap_b32 %0, %1" : "+v"(Fb), "+v"(Gb));
            asm("v_permlane16_swap_b32 %0, %1" : "+v"(Fb), "+v"(Gb));
            unsigned wds[4] = { Fa, Fb, Ga, Gb };      // words 0..3 of A-frag
            ap[s] = *(const s8v*)wds;
        }

        // ---- O += P V : A=P (row=q=lr), B=V from swizzled LDS
        __builtin_amdgcn_s_setprio(1);
#pragma unroll
        for (int f = 0; f < 4; ++f)
#pragma unroll
            for (int s = 0; s < 2; ++s) {
                const s8v bv = *(const s8v*)(Vl + (f * 16 + lr) * 128
                                             + (((s * 4 + g) * 16) ^ ((lr & 7) << 4)));
                acc[f] = __builtin_amdgcn_mfma_f32_16x16x32_bf16(ap[s], bv, acc[f], 0, 0, 0);
            }
        __builtin_amdgcn_s_setprio(0);

        if (kt < kend) {
            ST(cur ^ 1);                     // vmcnt wait: loads ≥1 tile old
            if (kt + 1 < kend) LD(kt + 2);   // issue next AFTER regs freed
            __syncthreads();                 // single barrier per tile
            cur ^= 1;
        }
    }

    // lsum: reduce across the 4 g-groups (same q=lr) -> full row sum
    lsum += __shfl_xor(lsum, 16, 64);
    lsum += __shfl_xor(lsum, 32, 64);

    const size_t pb = ((size_t)(b * QT_TILES + qt) * NCH + c);
    unsigned short* const Op = Opart + pb * 4096;
#pragma unroll
    for (int f = 0; f < 4; ++f)
#pragma unroll
        for (int r = 0; r < 4; ++r)
            Op[(w * 16 + g * 4 + r) * 64 + f * 16 + lr] = f2bf(acc[f][r]);
    if (l < 16)
        lpart[pb * 64 + w * 16 + l] = lsum;
}

// ---------------------------------------------------------------------------
// Kernel 3: combine bf16 partials: out = sum_c O_c / sum_c l_c
// ---------------------------------------------------------------------------
__global__ __launch_bounds__(256) void combine_kernel(
    const unsigned short* __restrict__ Opart, const float* __restrict__ lpart,
    float* __restrict__ out)
{
    const int idx = blockIdx.x * 256 + threadIdx.x;    // over NROWS*16
    const int row = idx >> 4, h4 = idx & 15;
    const int b = row >> 11, t = row & 2047;
    const int qt = t >> 6, r = t & 63;
    const int nch = (qt >> 2) + 1;                     // floor(qt/TPC)+1

    float4 os = make_float4(0.f, 0.f, 0.f, 0.f);
    float ls = 0.f;
    const size_t base = (size_t)(b * QT_TILES + qt) * NCH;
    for (int cc = 0; cc < nch; ++cc) {
        ushort4 v = *(const ushort4*)&Opart[(base + cc) * 4096 + r * 64 + h4 * 4];
        os.x += bf2f(v.x); os.y += bf2f(v.y); os.z += bf2f(v.z); os.w += bf2f(v.w);
        ls += lpart[(base + cc) * 64 + r];
    }
    float inv = 1.0f / ls;
    ((float4*)out)[idx] = make_float4(os.x * inv, os.y * inv, os.z * inv, os.w * inv);
}

// ---------------------------------------------------------------------------
extern "C" void kernel_launch(void* const* d_in, const int* in_sizes, int n_in,
                              void* d_out, int out_size, void* d_ws, size_t ws_size,
                              hipStream_t stream)
{
    const float* x  = (const float*)d_in[0];
    const float* Wq = (const float*)d_in[1];
    const float* Wk = (const float*)d_in[2];
    const float* Wv = (const float*)d_in[3];
    float* out = (float*)d_out;

    char* ws = (char*)d_ws;
    unsigned short* Wt = (unsigned short*)(ws);                    // 159,744 B
    unsigned short* Qb = (unsigned short*)(ws + 163840);           // 2 MB
    unsigned short* Kb = (unsigned short*)(ws + 163840 + 2097152);
    unsigned short* Vt = (unsigned short*)(ws + 163840 + 2 * 2097152);
    unsigned short* Opart = (unsigned short*)(ws + 163840 + 3 * 2097152); // 16 MB bf16
    float* lpart = (float*)(ws + 163840 + 3 * 2097152 + 16777216); // 512 KB

    wprep_kernel<<<(3 * H_DIM * KPAD + 255) / 256, 256, 0, stream>>>(Wq, Wk, Wv, Wt);
    proj_kernel<<<NROWS / 16, 256, 0, stream>>>(x, Wt, Qb, Kb, Vt);
    attn_kernel<<<dim3(NCH, QT_TILES, B_SZ), 256, 0, stream>>>(Qb, Kb, Vt, Opart, lpart);
    combine_kernel<<<(NROWS * H_DIM / 4) / 256, 256, 0, stream>>>(Opart, lpart, out);
}

// Round 7
// 43.769 us; speedup vs baseline: 1.3152x; 1.1712x over previous
//
#include <hip/hip_runtime.h>
#include <math.h>

#define B_SZ   8
#define T_SEQ  2048
#define C_DIM  400
#define H_DIM  64
#define NROWS  (B_SZ * T_SEQ)       // 16384
#define QT_TILES (T_SEQ / 64)       // 32
#define LDSTR  424                  // proj LDS row stride (elems)
#define NCH    8                    // max key chunks per q-tile
#define TPC    4                    // key tiles (of 64) per chunk
#define NKS    13                   // k-steps of 32 (416 padded)

typedef short s8v  __attribute__((ext_vector_type(8)));   // 8 bf16 (4 VGPRs)
typedef float f32x4 __attribute__((ext_vector_type(4)));
typedef unsigned u32x4 __attribute__((ext_vector_type(4)));

__device__ __forceinline__ unsigned short f2bf(float f) {
    unsigned int u = __float_as_uint(f);
    u = (u + 0x7FFFu + ((u >> 16) & 1u)) >> 16;   // RNE
    return (unsigned short)u;
}

__device__ __forceinline__ float bf2f(unsigned short u) {
    return __uint_as_float((unsigned)u << 16);
}

__device__ __forceinline__ unsigned cvtpk_bf16(float lo, float hi) {
    unsigned r;
    asm("v_cvt_pk_bf16_f32 %0, %1, %2" : "=v"(r) : "v"(lo), "v"(hi));
    return r;
}

// ---------------------------------------------------------------------------
// Kernel 0: fragment-packed weights.
// WtP[((f*13+ks)*64+lane)*8+j] = W_{f>>2}[ks*32+(lane>>4)*8+j][(f&3)*16+(lane&15)]
// (bf16, k zero-padded to 416; Wq pre-scaled by 1/8*log2(e)).
// proj's B-frag load becomes one coalesced 1KB read per (f,ks).
// ---------------------------------------------------------------------------
__global__ __launch_bounds__(256) void wprep_kernel(
    const float* __restrict__ Wq, const float* __restrict__ Wk,
    const float* __restrict__ Wv, unsigned short* __restrict__ WtP)
{
    int idx = blockIdx.x * 256 + threadIdx.x;          // over 12*13*512 = 79872
    int j    = idx & 7;
    int lane = (idx >> 3) & 63;
    int fks  = idx >> 9;                               // f*13 + ks
    int f    = fks / NKS;
    int ks   = fks - f * NKS;
    int m    = f >> 2;
    int col  = (f & 3) * 16 + (lane & 15);
    int k    = ks * 32 + (lane >> 4) * 8 + j;
    const float* W = (m == 0) ? Wq : (m == 1) ? Wk : Wv;
    float v = (k < C_DIM) ? W[k * H_DIM + col] : 0.0f;
    if (m == 0) v *= 0.125f * 1.44269504088896f;       // 1/sqrt(64) * log2(e)
    WtP[idx] = f2bf(v);
}

// ---------------------------------------------------------------------------
// Kernel 1: QKV projection via MFMA.  Block = 32-row A-tile (27KB LDS,
// 5 blocks/CU), wave = 3 N-frags x 2 row-groups.  W traffic halved vs M=16;
// B-frag loads fully coalesced from packed WtP.
// ---------------------------------------------------------------------------
__global__ __launch_bounds__(256) void proj_kernel(
    const float* __restrict__ x, const unsigned short* __restrict__ WtP,
    unsigned short* __restrict__ Qb, unsigned short* __restrict__ Kb,
    unsigned short* __restrict__ Vt)
{
    __shared__ unsigned short xl[32 * LDSTR];          // 27,136 B
    const int tid = threadIdx.x;
    const int tile = blockIdx.x;                       // 32-row tile, 0..511

    // stage 32 rows x 400 fp32 -> bf16 LDS (pad 400..415 with zeros)
    const float4* __restrict__ x4 = (const float4*)x;
    for (int idx = tid; idx < 32 * 104; idx += 256) {
        int row = idx / 104, c4 = idx - row * 104;
        ushort4 wv;
        if (c4 < 100) {
            float4 v = x4[(size_t)(tile * 32 + row) * 100 + c4];
            wv.x = f2bf(v.x); wv.y = f2bf(v.y); wv.z = f2bf(v.z); wv.w = f2bf(v.w);
        } else { wv.x = wv.y = wv.z = wv.w = 0; }
        *(ushort4*)&xl[row * LDSTR + c4 * 4] = wv;
    }
    __syncthreads();

    const int w = tid >> 6, l = tid & 63;
    const int lr = l & 15, g = l >> 4;

    f32x4 acc[3][2];
#pragma unroll
    for (int fl = 0; fl < 3; ++fl)
#pragma unroll
        for (int rg = 0; rg < 2; ++rg) acc[fl][rg] = (f32x4)0.f;

    const char* const Wp = (const char*)WtP;
    for (int ks = 0; ks < NKS; ++ks) {
        s8v a0 = *(const s8v*)&xl[lr        * LDSTR + ks * 32 + g * 8];
        s8v a1 = *(const s8v*)&xl[(16 + lr) * LDSTR + ks * 32 + g * 8];
#pragma unroll
        for (int fl = 0; fl < 3; ++fl) {
            int f = w * 3 + fl;                         // global N-frag 0..11
            const s8v b = *(const s8v*)(Wp + ((f * NKS + ks) << 10) + (l << 4));
            acc[fl][0] = __builtin_amdgcn_mfma_f32_16x16x32_bf16(a0, b, acc[fl][0], 0, 0, 0);
            acc[fl][1] = __builtin_amdgcn_mfma_f32_16x16x32_bf16(a1, b, acc[fl][1], 0, 0, 0);
        }
    }

#pragma unroll
    for (int fl = 0; fl < 3; ++fl) {
        int f = w * 3 + fl;
        int m = f >> 2, col = (f & 3) * 16 + lr;
#pragma unroll
        for (int rg = 0; rg < 2; ++rg)
#pragma unroll
            for (int r = 0; r < 4; ++r) {
                int row_g = tile * 32 + rg * 16 + g * 4 + r;
                unsigned short bv = f2bf(acc[fl][rg][r]);
                if (m == 0)      Qb[(size_t)row_g * H_DIM + col] = bv;
                else if (m == 1) Kb[(size_t)row_g * H_DIM + col] = bv;
                else {
                    int b = row_g >> 11, t = row_g & 2047;
                    Vt[((size_t)b * H_DIM + col) * T_SEQ + t] = bv;
                }
            }
    }
}

// ---------------------------------------------------------------------------
// Kernel 2: flash attention partials via MFMA (r6 structure, wave=16q,
// depth-2 prefetch, single barrier per tile).  This round: diag branch
// hoisted (mask-free fast path on 87% of tiles), tree lsum, bit_cast pack.
// ---------------------------------------------------------------------------
__global__ __launch_bounds__(256) void attn_kernel(
    const unsigned short* __restrict__ Qb, const unsigned short* __restrict__ Kb,
    const unsigned short* __restrict__ Vt,
    unsigned short* __restrict__ Opart, float* __restrict__ lpart)
{
    const int c  = blockIdx.x;
    const int qt = blockIdx.y;
    const int b  = blockIdx.z;
    if (c * TPC > qt) return;                          // empty chunk
    const int kt0 = c * TPC;
    const int kend = min(kt0 + (TPC - 1), qt);

    __shared__ char smem[2][16384];                    // 2 x (K 8KB + V 8KB)

    const int tid = threadIdx.x;
    const int w = tid >> 6, l = tid & 63;
    const int lr = l & 15, g = l >> 4;
    const int q0 = qt * 64 + w * 16;                   // wave's first q-row

    // staging geometry: thread covers rows r0, r0+32 of K and of V
    const int r0 = tid >> 3;                           // 0..31
    const int ch = tid & 7;
    const int swz = (ch * 16) ^ ((r0 & 7) << 4);       // (r0+32)&7 == r0&7
    const char* const Kg = (const char*)(Kb + (size_t)b * T_SEQ * H_DIM);
    const char* const Vg = (const char*)(Vt + (size_t)b * H_DIM * T_SEQ);

    uint4 kA, kB, vA, vB;
    auto LD = [&](int kt) {
        kA = *(const uint4*)(Kg + (size_t)(kt * 64 + r0     ) * 128 + ch * 16);
        kB = *(const uint4*)(Kg + (size_t)(kt * 64 + r0 + 32) * 128 + ch * 16);
        vA = *(const uint4*)(Vg + (size_t)(r0     ) * 4096 + kt * 128 + ch * 16);
        vB = *(const uint4*)(Vg + (size_t)(r0 + 32) * 4096 + kt * 128 + ch * 16);
    };
    auto ST = [&](int buf) {
        char* Kl = smem[buf];
        char* Vl = smem[buf] + 8192;
        *(uint4*)(Kl + r0 * 128 + swz)        = kA;
        *(uint4*)(Kl + (r0 + 32) * 128 + swz) = kB;
        *(uint4*)(Vl + r0 * 128 + swz)        = vA;
        *(uint4*)(Vl + (r0 + 32) * 128 + swz) = vB;
    };

    // Q B-frags (2 k-steps): lane holds Q[q0+lr][g*8+j] — pre-scaled bf16
    s8v aq[2];
#pragma unroll
    for (int s = 0; s < 2; ++s)
        aq[s] = *(const s8v*)&Qb[((size_t)b * T_SEQ + q0 + lr) * H_DIM + s * 32 + g * 8];

    f32x4 acc[4];
#pragma unroll
    for (int f = 0; f < 4; ++f) acc[f] = (f32x4)0.f;
    float lsum = 0.f;

    LD(kt0); ST(0);                                    // prologue (one stall)
    if (kt0 < kend) LD(kt0 + 1);                       // depth-2 prefetch seed
    __syncthreads();
    int cur = 0;

    for (int kt = kt0; kt <= kend; ++kt) {
        char* const Kl = smem[cur];
        char* const Vl = smem[cur] + 8192;

        // ---- S^T = K Q^T : sacc[f][r] = S[key=kt*64+f*16+g*4+r][q=q0+lr]
        f32x4 sacc[4];
#pragma unroll
        for (int f = 0; f < 4; ++f) sacc[f] = (f32x4)0.f;
        __builtin_amdgcn_s_setprio(1);
#pragma unroll
        for (int f = 0; f < 4; ++f)
#pragma unroll
            for (int s = 0; s < 2; ++s) {
                const s8v ak = *(const s8v*)(Kl + (f * 16 + lr) * 128
                                             + (((s * 4 + g) * 16) ^ ((lr & 7) << 4)));
                sacc[f] = __builtin_amdgcn_mfma_f32_16x16x32_bf16(ak, aq[s], sacc[f], 0, 0, 0);
            }
        __builtin_amdgcn_s_setprio(0);

        // ---- exp2 (+ mask only on the one diagonal tile), tree lsum
        float p[4][4];
        if (kt == qt) {
            const int q_my = q0 + lr;
#pragma unroll
            for (int f = 0; f < 4; ++f)
#pragma unroll
                for (int r = 0; r < 4; ++r) {
                    float pv = __builtin_amdgcn_exp2f(sacc[f][r]);
                    p[f][r] = ((kt * 64 + f * 16 + g * 4 + r) > q_my) ? 0.0f : pv;
                }
        } else {
#pragma unroll
            for (int f = 0; f < 4; ++f)
#pragma unroll
                for (int r = 0; r < 4; ++r)
                    p[f][r] = __builtin_amdgcn_exp2f(sacc[f][r]);
        }
#pragma unroll
        for (int f = 0; f < 4; ++f)
            lsum += (p[f][0] + p[f][1]) + (p[f][2] + p[f][3]);

        // ---- P -> bf16 A-frags in-register (cvt_pk + permlane, verified r3/4)
        s8v ap[2];
#pragma unroll
        for (int s = 0; s < 2; ++s) {
            unsigned Fa = cvtpk_bf16(p[2 * s][0],     p[2 * s][1]);
            unsigned Fb = cvtpk_bf16(p[2 * s][2],     p[2 * s][3]);
            unsigned Ga = cvtpk_bf16(p[2 * s + 1][0], p[2 * s + 1][1]);
            unsigned Gb = cvtpk_bf16(p[2 * s + 1][2], p[2 * s + 1][3]);
            asm("v_permlane32_swap_b32 %0, %1" : "+v"(Fa), "+v"(Ga));
            asm("v_permlane16_swap_b32 %0, %1" : "+v"(Fa), "+v"(Ga));
            asm("v_permlane32_swap_b32 %0, %1" : "+v"(Fb), "+v"(Gb));
            asm("v_permlane16_swap_b32 %0, %1" : "+v"(Fb), "+v"(Gb));
            u32x4 wv; wv.x = Fa; wv.y = Fb; wv.z = Ga; wv.w = Gb;
            ap[s] = __builtin_bit_cast(s8v, wv);
        }

        // ---- O += P V : A=P (row=q=lr), B=V from swizzled LDS
        __builtin_amdgcn_s_setprio(1);
#pragma unroll
        for (int f = 0; f < 4; ++f)
#pragma unroll
            for (int s = 0; s < 2; ++s) {
                const s8v bv = *(const s8v*)(Vl + (f * 16 + lr) * 128
                                             + (((s * 4 + g) * 16) ^ ((lr & 7) << 4)));
                acc[f] = __builtin_amdgcn_mfma_f32_16x16x32_bf16(ap[s], bv, acc[f], 0, 0, 0);
            }
        __builtin_amdgcn_s_setprio(0);

        if (kt < kend) {
            ST(cur ^ 1);                     // vmcnt wait: loads ≥1 tile old
            if (kt + 1 < kend) LD(kt + 2);   // issue next AFTER regs freed
            __syncthreads();                 // single barrier per tile
            cur ^= 1;
        }
    }

    // lsum: reduce across the 4 g-groups (same q=lr) -> full row sum
    lsum += __shfl_xor(lsum, 16, 64);
    lsum += __shfl_xor(lsum, 32, 64);

    const size_t pb = ((size_t)(b * QT_TILES + qt) * NCH + c);
    unsigned short* const Op = Opart + pb * 4096;
#pragma unroll
    for (int f = 0; f < 4; ++f)
#pragma unroll
        for (int r = 0; r < 4; ++r)
            Op[(w * 16 + g * 4 + r) * 64 + f * 16 + lr] = f2bf(acc[f][r]);
    if (l < 16)
        lpart[pb * 64 + w * 16 + l] = lsum;
}

// ---------------------------------------------------------------------------
// Kernel 3: combine bf16 partials: out = sum_c O_c / sum_c l_c
// ---------------------------------------------------------------------------
__global__ __launch_bounds__(256) void combine_kernel(
    const unsigned short* __restrict__ Opart, const float* __restrict__ lpart,
    float* __restrict__ out)
{
    const int idx = blockIdx.x * 256 + threadIdx.x;    // over NROWS*16
    const int row = idx >> 4, h4 = idx & 15;
    const int b = row >> 11, t = row & 2047;
    const int qt = t >> 6, r = t & 63;
    const int nch = (qt >> 2) + 1;                     // floor(qt/TPC)+1

    float4 os = make_float4(0.f, 0.f, 0.f, 0.f);
    float ls = 0.f;
    const size_t base = (size_t)(b * QT_TILES + qt) * NCH;
    for (int cc = 0; cc < nch; ++cc) {
        ushort4 v = *(const ushort4*)&Opart[(base + cc) * 4096 + r * 64 + h4 * 4];
        os.x += bf2f(v.x); os.y += bf2f(v.y); os.z += bf2f(v.z); os.w += bf2f(v.w);
        ls += lpart[(base + cc) * 64 + r];
    }
    float inv = 1.0f / ls;
    ((float4*)out)[idx] = make_float4(os.x * inv, os.y * inv, os.z * inv, os.w * inv);
}

// ---------------------------------------------------------------------------
extern "C" void kernel_launch(void* const* d_in, const int* in_sizes, int n_in,
                              void* d_out, int out_size, void* d_ws, size_t ws_size,
                              hipStream_t stream)
{
    const float* x  = (const float*)d_in[0];
    const float* Wq = (const float*)d_in[1];
    const float* Wk = (const float*)d_in[2];
    const float* Wv = (const float*)d_in[3];
    float* out = (float*)d_out;

    char* ws = (char*)d_ws;
    unsigned short* WtP = (unsigned short*)(ws);                   // 159,744 B
    unsigned short* Qb = (unsigned short*)(ws + 163840);           // 2 MB
    unsigned short* Kb = (unsigned short*)(ws + 163840 + 2097152);
    unsigned short* Vt = (unsigned short*)(ws + 163840 + 2 * 2097152);
    unsigned short* Opart = (unsigned short*)(ws + 163840 + 3 * 2097152); // 16 MB bf16
    float* lpart = (float*)(ws + 163840 + 3 * 2097152 + 16777216); // 512 KB

    wprep_kernel<<<(12 * NKS * 512) / 256, 256, 0, stream>>>(Wq, Wk, Wv, WtP);
    proj_kernel<<<NROWS / 32, 256, 0, stream>>>(x, WtP, Qb, Kb, Vt);
    attn_kernel<<<dim3(NCH, QT_TILES, B_SZ), 256, 0, stream>>>(Qb, Kb, Vt, Opart, lpart);
    combine_kernel<<<(NROWS * H_DIM / 4) / 256, 256, 0, stream>>>(Opart, lpart, out);
}